// Round 1
// baseline (316.517 us; speedup 1.0000x reference)
//
#include <hip/hip_runtime.h>
#include <cmath>

#define NGRAPHS 1024
#define ZDIM 16
#define NB 10
#define SHD 16
#define FEAT 2560   // 16 z * 10 b * 16 sh
#define CHUNK 64
#define CPAD (CHUNK + 4)   // +4 floats: breaks power-of-2 bank aliasing for transposed rows

// 2048 blocks: block (g = bid>>1, h = bid&1) processes half of graph g's nodes.
// Halves combine via last-finisher ticket in workspace:
//   both publish unscaled partials to ws + threadfence + atomicAdd(ticket);
//   second finisher reads partner's partial (agent-scope coherent loads),
//   adds its own (still in LDS), divides by full cnt, writes out.
// Deadlock-free: no spinning, whoever arrives second does the merge.
__global__ __launch_bounds__(256, 6) void yfe_kernel(
    const float* __restrict__ xin,
    const float* __restrict__ pos,
    const int* __restrict__ batch,
    float* __restrict__ out,
    int* __restrict__ tick,      // ws: NGRAPHS ints, zeroed by memset before launch
    float* __restrict__ wpart,   // ws: 2*NGRAPHS*FEAT floats (partials)
    int n_nodes)
{
    const int g = blockIdx.x >> 1;
    const int h = blockIdx.x & 1;
    const int tid = threadIdx.x;
    const int n = n_nodes;

    __shared__ int s_red[8];
    __shared__ __align__(16) float s_xT[ZDIM][CPAD];
    __shared__ __align__(16) float s_shA[SHD][CPAD];   // sh[m] * bvA
    __shared__ __align__(16) float s_shB[SHD][CPAD];   // sh[m] * bvB
    __shared__ __align__(16) unsigned int s_ib4[CHUNK / 4];  // 4 ib bytes per word
    __shared__ __align__(16) float s_out[FEAT];

    // ---- fused segment-bound search (batch sorted ascending) ----
    // lb(v) = first i with batch[i] >= v. start = lb(g), end = lb(g+1).
    {
        const int pos1 = (int)(((long long)tid * n) >> 8);
        const int v = batch[pos1];
        const unsigned long long balA = __ballot(v < g);
        const unsigned long long balB = __ballot(v < g + 1);
        if ((tid & 63) == 0) {
            s_red[tid >> 6]       = __popcll(balA);
            s_red[4 + (tid >> 6)] = __popcll(balB);
        }
    }
    __syncthreads();
    int start, end;
    {
        const int KA = s_red[0] + s_red[1] + s_red[2] + s_red[3];
        const int KB = s_red[4] + s_red[5] + s_red[6] + s_red[7];
        const int loA = (KA == 0) ? 0 : (int)(((long long)(KA - 1) * n) >> 8) + 1;
        const int hiA = (KA == 256) ? n : (int)(((long long)KA * n) >> 8);
        const int loB = (KB == 0) ? 0 : (int)(((long long)(KB - 1) * n) >> 8) + 1;
        const int hiB = (KB == 256) ? n : (int)(((long long)KB * n) >> 8);
        __syncthreads();
        // Level 2: window width <= ceil(n/256) <= 196 < 256 threads.
        const int pA = loA + tid;
        const int pB = loB + tid;
        const int prA = (pA < hiA) ? (batch[pA] < g) : 0;
        const int prB = (pB < hiB) ? (batch[pB] < g + 1) : 0;
        const unsigned long long balA = __ballot(prA);
        const unsigned long long balB = __ballot(prB);
        if ((tid & 63) == 0) {
            s_red[tid >> 6]       = __popcll(balA);
            s_red[4 + (tid >> 6)] = __popcll(balB);
        }
        __syncthreads();
        start = loA + s_red[0] + s_red[1] + s_red[2] + s_red[3];
        end   = loB + s_red[4] + s_red[5] + s_red[6] + s_red[7];
    }
    const int cnt = end - start;          // FULL graph count (for the mean)
    const int mid = start + ((cnt + 1) >> 1);
    const int hstart = h ? mid : start;   // this block's node half
    const int hend   = h ? end : mid;

    const int zi  = tid >> 4;
    const int shi = tid & 15;
    const int l   = (shi >= 9) ? 3 : (shi >= 4) ? 2 : (shi >= 1) ? 1 : 0;
    const int m   = shi - l * l;
    const int w   = 2 * l + 1;
    const int off = (l == 0) ? 0 : (l == 1) ? 160 : (l == 2) ? 640 : 1440;
    const int fbase = off + zi * 10 * w + m;   // out index for b=0; +b*w

    float acc[NB];
#pragma unroll
    for (int b = 0; b < NB; ++b) acc[b] = 0.0f;

    // c = SMOOTH_FINITE_C * e^2 * sqrt(NBASIS)
    const float CB = (float)(1.14136 * 7.389056098930650 * 3.1622776601683795);

    for (int nb0 = hstart; nb0 < hend; nb0 += CHUNK) {
        const int nrem  = min(CHUNK, hend - nb0);
        const int nrem4 = (nrem + 3) & ~3;
        __syncthreads();   // protect previous iteration's LDS reads
        // stage x TRANSPOSED: thread handles one float4 of x (coalesced 16B/lane reads)
        for (int idx = tid; idx < nrem * 4; idx += 256) {
            const int c = idx >> 2, zq = (idx & 3) * 4;
            const float4 xv = *(const float4*)(xin + (size_t)(nb0 + c) * ZDIM + zq);
            s_xT[zq + 0][c] = xv.x;
            s_xT[zq + 1][c] = xv.y;
            s_xT[zq + 2][c] = xv.z;
            s_xT[zq + 3][c] = xv.w;
        }
        // stage sh * bv (pre-multiplied) + packed ib byte, one thread per node
        if (tid < nrem) {
            const int node = nb0 + tid;
            const float px = pos[node * 3 + 0];
            const float py = pos[node * 3 + 1];
            const float pz = pos[node * 3 + 2];
            const float r2 = px * px + py * py + pz * pz;
            const float rinv = rsqrtf(r2);
            const float X = px * rinv, Y = py * rinv, Z = pz * rinv;
            const float x2 = X * X, y2 = Y * Y, z2 = Z * Z;
            const float x2z2 = x2 + z2;
            const float s3  = 1.7320508075688772f;
            const float s5  = 2.2360679774997896f;
            const float s7  = 2.6457513110645907f;
            const float s15 = 3.8729833462074170f;
            const float c42_6  = 1.0801234497346435f;   // sqrt(42)/6
            const float c168_8 = 1.6201851746019651f;   // sqrt(168)/8
            const float sh2_0 = s15 * X * Z;
            const float sh2_1 = s15 * X * Y;
            const float sh2_2 = s5 * (y2 - 0.5f * x2z2);
            const float sh2_3 = s15 * Y * Z;
            const float sh2_4 = 0.5f * s15 * (z2 - x2);
            float sh[SHD];
            sh[0]  = 1.0f;
            sh[1]  = s3 * X;
            sh[2]  = s3 * Y;
            sh[3]  = s3 * Z;
            sh[4]  = sh2_0;
            sh[5]  = sh2_1;
            sh[6]  = sh2_2;
            sh[7]  = sh2_3;
            sh[8]  = sh2_4;
            sh[9]  = c42_6 * (sh2_0 * Z + sh2_4 * X);
            sh[10] = s7 * sh2_0 * Y;
            sh[11] = c168_8 * (4.0f * y2 - x2z2) * X;
            sh[12] = 0.5f * s7 * Y * (2.0f * y2 - 3.0f * x2z2);
            sh[13] = c168_8 * Z * (4.0f * y2 - x2z2);
            sh[14] = s7 * sh2_4 * Y;
            sh[15] = c42_6 * (sh2_4 * Z - sh2_0 * X);
            // radial basis: t = 1.1*d; active b in (t-2, t) -> at most {ib, ib+1}
            const float d = r2 * rinv;     // sqrt(r2)
            const float t = d * 1.1f;
            int ib = (int)floorf(t) - 1;
            ib = min(max(ib, 0), 8);
            float bvA = 0.0f, bvB = 0.0f;
            {
                const float u1 = t - (float)ib, u2 = (float)(ib + 2) - t;
                if (u1 > 0.0f && u2 > 0.0f) bvA = CB * __expf(-1.0f / u1 - 1.0f / u2);
                const float v1 = t - (float)(ib + 1), v2 = (float)(ib + 3) - t;
                if (v1 > 0.0f && v2 > 0.0f) bvB = CB * __expf(-1.0f / v1 - 1.0f / v2);
            }
#pragma unroll
            for (int k = 0; k < SHD; ++k) {
                s_shA[k][tid] = sh[k] * bvA;
                s_shB[k][tid] = sh[k] * bvB;
            }
            ((unsigned char*)s_ib4)[tid] = (unsigned char)ib;
        } else if (tid < nrem4) {
            // zero-fill pad columns so the 4-wide inner loop reads finite zeros
#pragma unroll
            for (int k = 0; k < SHD; ++k) {
                s_xT[k][tid] = 0.0f; s_shA[k][tid] = 0.0f; s_shB[k][tid] = 0.0f;
            }
            ((unsigned char*)s_ib4)[tid] = 0;
        }
        __syncthreads();

#define ACC1(XQ, SA, SB, IB_)                                                    \
        {                                                                        \
            const float xq_ = (XQ);                                              \
            switch (IB_) {                                                       \
                case 0: acc[0] += xq_ * (SA); acc[1] += xq_ * (SB); break;       \
                case 1: acc[1] += xq_ * (SA); acc[2] += xq_ * (SB); break;       \
                case 2: acc[2] += xq_ * (SA); acc[3] += xq_ * (SB); break;       \
                case 3: acc[3] += xq_ * (SA); acc[4] += xq_ * (SB); break;       \
                case 4: acc[4] += xq_ * (SA); acc[5] += xq_ * (SB); break;       \
                case 5: acc[5] += xq_ * (SA); acc[6] += xq_ * (SB); break;       \
                case 6: acc[6] += xq_ * (SA); acc[7] += xq_ * (SB); break;       \
                case 7: acc[7] += xq_ * (SA); acc[8] += xq_ * (SB); break;       \
                default: acc[8] += xq_ * (SA); acc[9] += xq_ * (SB); break;      \
            }                                                                    \
        }

#pragma unroll 2
        for (int c = 0; c < nrem4; c += 4) {
            const float4 xv = *(const float4*)&s_xT[zi][c];
            const float4 sA = *(const float4*)&s_shA[shi][c];
            const float4 sB = *(const float4*)&s_shB[shi][c];
            const unsigned int ibw =
                (unsigned int)__builtin_amdgcn_readfirstlane((int)s_ib4[c >> 2]);
            ACC1(xv.x, sA.x, sB.x, (int)(ibw & 255u));
            ACC1(xv.y, sA.y, sB.y, (int)((ibw >> 8) & 255u));
            ACC1(xv.z, sA.z, sB.z, (int)((ibw >> 16) & 255u));
            ACC1(xv.w, sA.w, sB.w, (int)(ibw >> 24));
        }
#undef ACC1
    }

    // ---- stage UNSCALED partial to LDS for coalesced publish ----
#pragma unroll
    for (int b = 0; b < NB; ++b) s_out[fbase + b * w] = acc[b];
    __syncthreads();

    // publish partial to workspace slot (g,h)
    float* myslot = wpart + (size_t)((g << 1) | h) * FEAT;
    {
        float4* ws4 = (float4*)myslot;
        const float4* so4 = (const float4*)s_out;
        for (int i = tid; i < FEAT / 4; i += 256) ws4[i] = so4[i];
    }
    __threadfence();        // device-scope: make stores visible before ticket
    __syncthreads();        // all threads' stores+fences precede tid0's ticket
    if (tid == 0)
        s_red[0] = __hip_atomic_fetch_add(&tick[g], 1, __ATOMIC_ACQ_REL,
                                          __HIP_MEMORY_SCOPE_AGENT);
    __syncthreads();
    if (s_red[0] == 0) return;   // first finisher: partial published, done

    // ---- last finisher merges: own partial (LDS) + partner partial (ws) ----
    const float scale = 1.0f / (float)max(cnt, 1);
    float* partner = wpart + (size_t)((g << 1) | (h ^ 1)) * FEAT;
    float* og = out + (size_t)g * FEAT;
    for (int i = tid; i < FEAT; i += 256) {
        const float pv = __hip_atomic_load(&partner[i], __ATOMIC_RELAXED,
                                           __HIP_MEMORY_SCOPE_AGENT);
        og[i] = (s_out[i] + pv) * scale;
    }
}

extern "C" void kernel_launch(void* const* d_in, const int* in_sizes, int n_in,
                              void* d_out, int out_size, void* d_ws, size_t ws_size,
                              hipStream_t stream) {
    const float* x   = (const float*)d_in[0];
    const float* pos = (const float*)d_in[1];
    const int* batch = (const int*)d_in[2];
    float* out = (float*)d_out;
    const int n_nodes = in_sizes[2];

    int* tick = (int*)d_ws;                               // NGRAPHS ints
    float* wpart = (float*)((char*)d_ws + 4096);          // 2*NGRAPHS*FEAT floats

    // zero the tickets each launch (graph-capture legal; replayed per iteration)
    hipMemsetAsync(d_ws, 0, NGRAPHS * sizeof(int), stream);

    hipLaunchKernelGGL(yfe_kernel, dim3(NGRAPHS * 2), dim3(256), 0, stream,
                       x, pos, batch, out, tick, wpart, n_nodes);
}

// Round 2
// 70.254 us; speedup vs baseline: 4.5053x; 4.5053x over previous
//
#include <hip/hip_runtime.h>
#include <cmath>

#define NGRAPHS 1024
#define ZDIM 16
#define NB 10
#define SHD 16
#define FEAT 2560   // 16 z * 10 b * 16 sh
#define CHUNK 128
#define CPAD (CHUNK + 4)   // +4 floats: breaks power-of-2 bank aliasing for transposed rows
#define WIN 1536           // windowed-search width: 6 elements per thread

// One block per graph. Thread ownership: tid -> (z = tid>>4, sh = tid&15);
// acc[10] = radial-basis dimension in registers.
// Radial basis is 2-sparse: only b in {ib, ib+1} nonzero per node, ib node-uniform.
// bvA/bvB are pre-multiplied into the staged sh rows, so the inner loop is
// 2 FMAs per node with 3xds_read_b128 + 1xds_read_b32 per 4 nodes.
//
// Segment search: batch is sorted, segment sizes ~Binomial(n, 1/1024) so both
// lb(g) and lb(g+1) lie within ~6.6 sigma of the uniform estimate. One
// 1536-wide coalesced window per block (block-private lines -> no cross-block
// hot-spot) replaces the old 2-round global search (one fewer dependent cold
// round; round 1 of the old scheme had all 1024 blocks hitting the SAME 256
// cache lines). Exact 2-round search kept as block-uniform fallback.
__global__ __launch_bounds__(256) void yfe_kernel(
    const float* __restrict__ xin,
    const float* __restrict__ pos,
    const int* __restrict__ batch,
    float* __restrict__ out,
    int n_nodes)
{
    const int g = blockIdx.x;
    const int tid = threadIdx.x;
    const int n = n_nodes;

    __shared__ int s_red[12];
    __shared__ __align__(16) float s_xT[ZDIM][CPAD];
    __shared__ __align__(16) float s_shA[SHD][CPAD];   // sh[m] * bvA
    __shared__ __align__(16) float s_shB[SHD][CPAD];   // sh[m] * bvB
    __shared__ __align__(16) unsigned int s_ib4[CHUNK / 4];  // 4 ib bytes per word
    __shared__ __align__(16) float s_out[FEAT];

    int start, end;
    bool window_ok = (n >= WIN);
    if (window_ok) {
        // ---- windowed local search: one cold round, block-private lines ----
        const int ctr = (int)(((long long)(2 * g + 1) * n) >> 11);  // (g+0.5)*n/1024
        int p0 = ctr - WIN / 2;
        if (p0 < 0) p0 = 0;
        if (p0 > n - WIN) p0 = n - WIN;
        int vals[6];
#pragma unroll
        for (int k = 0; k < 6; ++k) vals[k] = batch[p0 + tid + k * 256];
        int wA = 0, wB = 0;
#pragma unroll
        for (int k = 0; k < 6; ++k) {
            wA += __popcll(__ballot(vals[k] < g));
            wB += __popcll(__ballot(vals[k] < g + 1));
        }
        if ((tid & 63) == 0) {
            s_red[tid >> 6]       = wA;   // identical across lanes of the wave
            s_red[4 + (tid >> 6)] = wB;
        }
        if (tid == 0)   s_red[8] = vals[0];   // batch[p0]
        if (tid == 255) s_red[9] = vals[5];   // batch[p0 + WIN - 1]
        __syncthreads();
        const int KA = s_red[0] + s_red[1] + s_red[2] + s_red[3];
        const int KB = s_red[4] + s_red[5] + s_red[6] + s_red[7];
        start = p0 + KA;
        end   = p0 + KB;
        // bracket validation: everything left of window < g, right of window >= g+1
        const bool left_ok  = (p0 == 0) || (s_red[8] < g);
        const bool right_ok = (p0 + WIN == n) || (s_red[9] >= g + 1);
        window_ok = left_ok && right_ok;      // block-uniform
        __syncthreads();                      // s_red reused below (fallback / epilogue)
    }
    if (!window_ok) {
        // ---- exact fallback: original 2-level strided search ----
        {
            const int pos1 = (int)(((long long)tid * n) >> 8);
            const int v = batch[pos1];
            const unsigned long long balA = __ballot(v < g);
            const unsigned long long balB = __ballot(v < g + 1);
            if ((tid & 63) == 0) {
                s_red[tid >> 6]       = __popcll(balA);
                s_red[4 + (tid >> 6)] = __popcll(balB);
            }
        }
        __syncthreads();
        const int KA = s_red[0] + s_red[1] + s_red[2] + s_red[3];
        const int KB = s_red[4] + s_red[5] + s_red[6] + s_red[7];
        const int loA = (KA == 0) ? 0 : (int)(((long long)(KA - 1) * n) >> 8) + 1;
        const int hiA = (KA == 256) ? n : (int)(((long long)KA * n) >> 8);
        const int loB = (KB == 0) ? 0 : (int)(((long long)(KB - 1) * n) >> 8) + 1;
        const int hiB = (KB == 256) ? n : (int)(((long long)KB * n) >> 8);
        __syncthreads();
        const int pA = loA + tid;
        const int pB = loB + tid;
        const int prA = (pA < hiA) ? (batch[pA] < g) : 0;
        const int prB = (pB < hiB) ? (batch[pB] < g + 1) : 0;
        const unsigned long long balA = __ballot(prA);
        const unsigned long long balB = __ballot(prB);
        if ((tid & 63) == 0) {
            s_red[tid >> 6]       = __popcll(balA);
            s_red[4 + (tid >> 6)] = __popcll(balB);
        }
        __syncthreads();
        start = loA + s_red[0] + s_red[1] + s_red[2] + s_red[3];
        end   = loB + s_red[4] + s_red[5] + s_red[6] + s_red[7];
        __syncthreads();
    }
    const int cnt = end - start;

    const int zi  = tid >> 4;
    const int shi = tid & 15;
    const int l   = (shi >= 9) ? 3 : (shi >= 4) ? 2 : (shi >= 1) ? 1 : 0;
    const int m   = shi - l * l;
    const int w   = 2 * l + 1;
    const int off = (l == 0) ? 0 : (l == 1) ? 160 : (l == 2) ? 640 : 1440;
    const int fbase = off + zi * 10 * w + m;   // out index for b=0; +b*w

    float acc[NB];
#pragma unroll
    for (int b = 0; b < NB; ++b) acc[b] = 0.0f;

    // c = SMOOTH_FINITE_C * e^2 * sqrt(NBASIS)
    const float CB = (float)(1.14136 * 7.389056098930650 * 3.1622776601683795);

    for (int nb0 = start; nb0 < end; nb0 += CHUNK) {
        const int nrem  = min(CHUNK, end - nb0);
        const int nrem4 = (nrem + 3) & ~3;
        __syncthreads();   // protect previous iteration's LDS reads
        // stage x TRANSPOSED: thread handles one float4 of x (coalesced 16B/lane reads)
        for (int idx = tid; idx < nrem * 4; idx += 256) {
            const int c = idx >> 2, zq = (idx & 3) * 4;
            const float4 xv = *(const float4*)(xin + (size_t)(nb0 + c) * ZDIM + zq);
            s_xT[zq + 0][c] = xv.x;
            s_xT[zq + 1][c] = xv.y;
            s_xT[zq + 2][c] = xv.z;
            s_xT[zq + 3][c] = xv.w;
        }
        // stage sh * bv (pre-multiplied) + packed ib byte, one thread per node
        if (tid < nrem) {
            const int node = nb0 + tid;
            const float px = pos[node * 3 + 0];
            const float py = pos[node * 3 + 1];
            const float pz = pos[node * 3 + 2];
            const float r2 = px * px + py * py + pz * pz;
            const float rinv = rsqrtf(r2);
            const float X = px * rinv, Y = py * rinv, Z = pz * rinv;
            const float x2 = X * X, y2 = Y * Y, z2 = Z * Z;
            const float x2z2 = x2 + z2;
            const float s3  = 1.7320508075688772f;
            const float s5  = 2.2360679774997896f;
            const float s7  = 2.6457513110645907f;
            const float s15 = 3.8729833462074170f;
            const float c42_6  = 1.0801234497346435f;   // sqrt(42)/6
            const float c168_8 = 1.6201851746019651f;   // sqrt(168)/8
            const float sh2_0 = s15 * X * Z;
            const float sh2_1 = s15 * X * Y;
            const float sh2_2 = s5 * (y2 - 0.5f * x2z2);
            const float sh2_3 = s15 * Y * Z;
            const float sh2_4 = 0.5f * s15 * (z2 - x2);
            float sh[SHD];
            sh[0]  = 1.0f;
            sh[1]  = s3 * X;
            sh[2]  = s3 * Y;
            sh[3]  = s3 * Z;
            sh[4]  = sh2_0;
            sh[5]  = sh2_1;
            sh[6]  = sh2_2;
            sh[7]  = sh2_3;
            sh[8]  = sh2_4;
            sh[9]  = c42_6 * (sh2_0 * Z + sh2_4 * X);
            sh[10] = s7 * sh2_0 * Y;
            sh[11] = c168_8 * (4.0f * y2 - x2z2) * X;
            sh[12] = 0.5f * s7 * Y * (2.0f * y2 - 3.0f * x2z2);
            sh[13] = c168_8 * Z * (4.0f * y2 - x2z2);
            sh[14] = s7 * sh2_4 * Y;
            sh[15] = c42_6 * (sh2_4 * Z - sh2_0 * X);
            // radial basis: t = 1.1*d; active b in (t-2, t) -> at most {ib, ib+1}
            const float d = r2 * rinv;     // sqrt(r2)
            const float t = d * 1.1f;
            int ib = (int)floorf(t) - 1;
            ib = min(max(ib, 0), 8);
            float bvA = 0.0f, bvB = 0.0f;
            {
                const float u1 = t - (float)ib, u2 = (float)(ib + 2) - t;
                if (u1 > 0.0f && u2 > 0.0f) bvA = CB * __expf(-1.0f / u1 - 1.0f / u2);
                const float v1 = t - (float)(ib + 1), v2 = (float)(ib + 3) - t;
                if (v1 > 0.0f && v2 > 0.0f) bvB = CB * __expf(-1.0f / v1 - 1.0f / v2);
            }
#pragma unroll
            for (int k = 0; k < SHD; ++k) {
                s_shA[k][tid] = sh[k] * bvA;
                s_shB[k][tid] = sh[k] * bvB;
            }
            ((unsigned char*)s_ib4)[tid] = (unsigned char)ib;
        } else if (tid < nrem4) {
            // zero-fill pad columns so the 4-wide inner loop reads finite zeros
            // (stale LDS could hold NaN bit patterns; 0*NaN = NaN)
#pragma unroll
            for (int k = 0; k < SHD; ++k) {
                s_xT[k][tid] = 0.0f; s_shA[k][tid] = 0.0f; s_shB[k][tid] = 0.0f;
            }
            ((unsigned char*)s_ib4)[tid] = 0;
        }
        __syncthreads();

#define ACC1(XQ, SA, SB, IB_)                                                    \
        {                                                                        \
            const float xq_ = (XQ);                                              \
            switch (IB_) {                                                       \
                case 0: acc[0] += xq_ * (SA); acc[1] += xq_ * (SB); break;       \
                case 1: acc[1] += xq_ * (SA); acc[2] += xq_ * (SB); break;       \
                case 2: acc[2] += xq_ * (SA); acc[3] += xq_ * (SB); break;       \
                case 3: acc[3] += xq_ * (SA); acc[4] += xq_ * (SB); break;       \
                case 4: acc[4] += xq_ * (SA); acc[5] += xq_ * (SB); break;       \
                case 5: acc[5] += xq_ * (SA); acc[6] += xq_ * (SB); break;       \
                case 6: acc[6] += xq_ * (SA); acc[7] += xq_ * (SB); break;       \
                case 7: acc[7] += xq_ * (SA); acc[8] += xq_ * (SB); break;       \
                default: acc[8] += xq_ * (SA); acc[9] += xq_ * (SB); break;      \
            }                                                                    \
        }

#pragma unroll 2
        for (int c = 0; c < nrem4; c += 4) {
            const float4 xv = *(const float4*)&s_xT[zi][c];
            const float4 sA = *(const float4*)&s_shA[shi][c];
            const float4 sB = *(const float4*)&s_shB[shi][c];
            const unsigned int ibw =
                (unsigned int)__builtin_amdgcn_readfirstlane((int)s_ib4[c >> 2]);
            ACC1(xv.x, sA.x, sB.x, (int)(ibw & 255u));
            ACC1(xv.y, sA.y, sB.y, (int)((ibw >> 8) & 255u));
            ACC1(xv.z, sA.z, sB.z, (int)((ibw >> 16) & 255u));
            ACC1(xv.w, sA.w, sB.w, (int)(ibw >> 24));
        }
#undef ACC1
    }

    // mean + stage to LDS for coalesced output
    const float scale = 1.0f / (float)max(cnt, 1);
#pragma unroll
    for (int b = 0; b < NB; ++b) s_out[fbase + b * w] = acc[b] * scale;
    __syncthreads();
    float4* og4 = (float4*)(out + (size_t)g * FEAT);
    const float4* so4 = (const float4*)s_out;
    for (int i = tid; i < FEAT / 4; i += 256) og4[i] = so4[i];
}

extern "C" void kernel_launch(void* const* d_in, const int* in_sizes, int n_in,
                              void* d_out, int out_size, void* d_ws, size_t ws_size,
                              hipStream_t stream) {
    const float* x   = (const float*)d_in[0];
    const float* pos = (const float*)d_in[1];
    const int* batch = (const int*)d_in[2];
    float* out = (float*)d_out;
    const int n_nodes = in_sizes[2];

    hipLaunchKernelGGL(yfe_kernel, dim3(NGRAPHS), dim3(256), 0, stream,
                       x, pos, batch, out, n_nodes);
}

// Round 3
// 65.736 us; speedup vs baseline: 4.8149x; 1.0687x over previous
//
#include <hip/hip_runtime.h>
#include <cmath>

#define NGRAPHS 1024
#define ZDIM 16
#define NB 10
#define SHD 16
#define FEAT 2560   // 16 z * 10 b * 16 sh
#define CHUNK 96           // max nodes staged per iteration (typ. segment ~49; loop handles overflow)
#define CSTRIDE 132        // >= CHUNK + 9*3 pad, rounded; 132 % 32 == 4 -> worst 2-way bank conflict (free)
#define WIN 1536           // windowed-search width: 6 elements per thread

// One block per graph. Thread ownership: tid -> (z = tid>>4, sh = tid&15).
// Radial basis is 2-sparse: only b in {ib, ib+1} nonzero per node, ib node-uniform.
//
// NEW vs r2: nodes are BUCKETED BY ib at staging time (wave ballot rank ->
// bucket-contiguous columns, each bucket padded to 4 with zeros). The inner
// loop is 9 compile-time-ib mini-loops: 3x ds_read_b128 + 8 v_fmac per 4
// nodes — no switch, no readfirstlane, no byte extraction, no branch bubbles.
// Node-threads issue their x row loads (4x float4) BEFORE the sh compute so
// the cold global latency hides under ~150 VALU ops.
__global__ __launch_bounds__(256) void yfe_kernel(
    const float* __restrict__ xin,
    const float* __restrict__ pos,
    const int* __restrict__ batch,
    float* __restrict__ out,
    int n_nodes)
{
    const int g = blockIdx.x;
    const int tid = threadIdx.x;
    const int n = n_nodes;

    __shared__ int s_red[12];
    __shared__ int s_cnt[2][9];      // per-wave bucket counts (waves 0,1 hold all node-threads)
    __shared__ __align__(16) float s_xT[ZDIM][CSTRIDE];
    __shared__ __align__(16) float s_shA[SHD][CSTRIDE];   // sh[m] * bvA, bucket-permuted
    __shared__ __align__(16) float s_shB[SHD][CSTRIDE];   // sh[m] * bvB, bucket-permuted
    __shared__ __align__(16) float s_out[FEAT];

    int start, end;
    bool window_ok = (n >= WIN);
    if (window_ok) {
        // ---- windowed local search: one cold round, block-private lines ----
        const int ctr = (int)(((long long)(2 * g + 1) * n) >> 11);  // (g+0.5)*n/1024
        int p0 = ctr - WIN / 2;
        if (p0 < 0) p0 = 0;
        if (p0 > n - WIN) p0 = n - WIN;
        int vals[6];
#pragma unroll
        for (int k = 0; k < 6; ++k) vals[k] = batch[p0 + tid + k * 256];
        int wA = 0, wB = 0;
#pragma unroll
        for (int k = 0; k < 6; ++k) {
            wA += __popcll(__ballot(vals[k] < g));
            wB += __popcll(__ballot(vals[k] < g + 1));
        }
        if ((tid & 63) == 0) {
            s_red[tid >> 6]       = wA;   // identical across lanes of the wave
            s_red[4 + (tid >> 6)] = wB;
        }
        if (tid == 0)   s_red[8] = vals[0];   // batch[p0]
        if (tid == 255) s_red[9] = vals[5];   // batch[p0 + WIN - 1]
        __syncthreads();
        const int KA = s_red[0] + s_red[1] + s_red[2] + s_red[3];
        const int KB = s_red[4] + s_red[5] + s_red[6] + s_red[7];
        start = p0 + KA;
        end   = p0 + KB;
        // bracket validation: everything left of window < g, right of window >= g+1
        const bool left_ok  = (p0 == 0) || (s_red[8] < g);
        const bool right_ok = (p0 + WIN == n) || (s_red[9] >= g + 1);
        window_ok = left_ok && right_ok;      // block-uniform
        __syncthreads();                      // s_red reused below (fallback)
    }
    if (!window_ok) {
        // ---- exact fallback: original 2-level strided search ----
        {
            const int pos1 = (int)(((long long)tid * n) >> 8);
            const int v = batch[pos1];
            const unsigned long long balA = __ballot(v < g);
            const unsigned long long balB = __ballot(v < g + 1);
            if ((tid & 63) == 0) {
                s_red[tid >> 6]       = __popcll(balA);
                s_red[4 + (tid >> 6)] = __popcll(balB);
            }
        }
        __syncthreads();
        const int KA = s_red[0] + s_red[1] + s_red[2] + s_red[3];
        const int KB = s_red[4] + s_red[5] + s_red[6] + s_red[7];
        const int loA = (KA == 0) ? 0 : (int)(((long long)(KA - 1) * n) >> 8) + 1;
        const int hiA = (KA == 256) ? n : (int)(((long long)KA * n) >> 8);
        const int loB = (KB == 0) ? 0 : (int)(((long long)(KB - 1) * n) >> 8) + 1;
        const int hiB = (KB == 256) ? n : (int)(((long long)KB * n) >> 8);
        __syncthreads();
        const int pA = loA + tid;
        const int pB = loB + tid;
        const int prA = (pA < hiA) ? (batch[pA] < g) : 0;
        const int prB = (pB < hiB) ? (batch[pB] < g + 1) : 0;
        const unsigned long long balA = __ballot(prA);
        const unsigned long long balB = __ballot(prB);
        if ((tid & 63) == 0) {
            s_red[tid >> 6]       = __popcll(balA);
            s_red[4 + (tid >> 6)] = __popcll(balB);
        }
        __syncthreads();
        start = loA + s_red[0] + s_red[1] + s_red[2] + s_red[3];
        end   = loB + s_red[4] + s_red[5] + s_red[6] + s_red[7];
        __syncthreads();
    }
    const int cnt = end - start;

    const int zi  = tid >> 4;
    const int shi = tid & 15;
    const int l   = (shi >= 9) ? 3 : (shi >= 4) ? 2 : (shi >= 1) ? 1 : 0;
    const int m   = shi - l * l;
    const int w   = 2 * l + 1;
    const int off = (l == 0) ? 0 : (l == 1) ? 160 : (l == 2) ? 640 : 1440;
    const int fbase = off + zi * 10 * w + m;   // out index for b=0; +b*w

    float acc[NB];
#pragma unroll
    for (int b = 0; b < NB; ++b) acc[b] = 0.0f;

    // c = SMOOTH_FINITE_C * e^2 * sqrt(NBASIS)
    const float CB = (float)(1.14136 * 7.389056098930650 * 3.1622776601683795);

    for (int nb0 = start; nb0 < end; nb0 += CHUNK) {
        const int nrem = min(CHUNK, end - nb0);
        __syncthreads();   // protect previous iteration's LDS reads

        // ---- zero all staging arrays (pads must read as 0.0; stale LDS may be NaN) ----
        {
            const float4 z4 = make_float4(0.f, 0.f, 0.f, 0.f);
            float4* zx = (float4*)s_xT;
            float4* za = (float4*)s_shA;
            float4* zb = (float4*)s_shB;
            for (int i = tid; i < (ZDIM * CSTRIDE) / 4; i += 256) {
                zx[i] = z4; za[i] = z4; zb[i] = z4;
            }
        }

        // ---- node-thread compute: issue x loads first, then sh/basis ----
        int   my_ib = 9;         // 9 = "no bucket" for non-node lanes
        int   my_rank = 0;
        float4 xr0, xr1, xr2, xr3;
        float sh[SHD];
        float bvA = 0.0f, bvB = 0.0f;
        if (tid < nrem) {
            const int node = nb0 + tid;
            const float4* xp = (const float4*)(xin + (size_t)node * ZDIM);
            xr0 = xp[0]; xr1 = xp[1]; xr2 = xp[2]; xr3 = xp[3];   // in flight under sh compute
            const float px = pos[node * 3 + 0];
            const float py = pos[node * 3 + 1];
            const float pz = pos[node * 3 + 2];
            const float r2 = px * px + py * py + pz * pz;
            const float rinv = rsqrtf(r2);
            const float X = px * rinv, Y = py * rinv, Z = pz * rinv;
            const float x2 = X * X, y2 = Y * Y, z2 = Z * Z;
            const float x2z2 = x2 + z2;
            const float s3  = 1.7320508075688772f;
            const float s5  = 2.2360679774997896f;
            const float s7  = 2.6457513110645907f;
            const float s15 = 3.8729833462074170f;
            const float c42_6  = 1.0801234497346435f;   // sqrt(42)/6
            const float c168_8 = 1.6201851746019651f;   // sqrt(168)/8
            const float sh2_0 = s15 * X * Z;
            const float sh2_1 = s15 * X * Y;
            const float sh2_2 = s5 * (y2 - 0.5f * x2z2);
            const float sh2_3 = s15 * Y * Z;
            const float sh2_4 = 0.5f * s15 * (z2 - x2);
            sh[0]  = 1.0f;
            sh[1]  = s3 * X;
            sh[2]  = s3 * Y;
            sh[3]  = s3 * Z;
            sh[4]  = sh2_0;
            sh[5]  = sh2_1;
            sh[6]  = sh2_2;
            sh[7]  = sh2_3;
            sh[8]  = sh2_4;
            sh[9]  = c42_6 * (sh2_0 * Z + sh2_4 * X);
            sh[10] = s7 * sh2_0 * Y;
            sh[11] = c168_8 * (4.0f * y2 - x2z2) * X;
            sh[12] = 0.5f * s7 * Y * (2.0f * y2 - 3.0f * x2z2);
            sh[13] = c168_8 * Z * (4.0f * y2 - x2z2);
            sh[14] = s7 * sh2_4 * Y;
            sh[15] = c42_6 * (sh2_4 * Z - sh2_0 * X);
            // radial basis: t = 1.1*d; active b in (t-2, t) -> at most {ib, ib+1}
            const float d = r2 * rinv;     // sqrt(r2)
            const float t = d * 1.1f;
            int ib = (int)floorf(t) - 1;
            ib = min(max(ib, 0), 8);
            {
                const float u1 = t - (float)ib, u2 = (float)(ib + 2) - t;
                if (u1 > 0.0f && u2 > 0.0f) bvA = CB * __expf(-1.0f / u1 - 1.0f / u2);
                const float v1 = t - (float)(ib + 1), v2 = (float)(ib + 3) - t;
                if (v1 > 0.0f && v2 > 0.0f) bvB = CB * __expf(-1.0f / v1 - 1.0f / v2);
            }
            my_ib = ib;
        }
        // ---- bucket ranking: 9 ballots on waves 0,1 (all node-threads live there) ----
        if (tid < 128) {   // wave-uniform branch
            const unsigned long long lt = (1ull << (unsigned)(tid & 63)) - 1ull;
#pragma unroll
            for (int v = 0; v < 9; ++v) {
                const unsigned long long bal = __ballot(my_ib == v);
                if (my_ib == v) my_rank = __popcll(bal & lt);
                if ((tid & 63) == 0) s_cnt[tid >> 6][v] = __popcll(bal);
            }
        }
        __syncthreads();

        // every thread: padded bucket starts (compile-time indexed)
        int cum[10];
        {
            cum[0] = 0;
#pragma unroll
            for (int v = 0; v < 9; ++v)
                cum[v + 1] = cum[v] + ((s_cnt[0][v] + s_cnt[1][v] + 3) & ~3);
        }

        // ---- stage into bucket-permuted columns ----
        if (tid < nrem) {
            // dest = bucket base (predicated prefix; no dynamic register indexing)
            int dest = my_rank;
            if (tid >= 64) dest += s_cnt[0][my_ib];     // wave-1 offset (dynamic LDS read: fine)
#pragma unroll
            for (int v = 0; v < 9; ++v) {
                const int pv = (s_cnt[0][v] + s_cnt[1][v] + 3) & ~3;
                dest += (v < my_ib) ? pv : 0;
            }
#pragma unroll
            for (int k = 0; k < SHD; ++k) {
                s_shA[k][dest] = sh[k] * bvA;
                s_shB[k][dest] = sh[k] * bvB;
            }
            s_xT[ 0][dest] = xr0.x; s_xT[ 1][dest] = xr0.y;
            s_xT[ 2][dest] = xr0.z; s_xT[ 3][dest] = xr0.w;
            s_xT[ 4][dest] = xr1.x; s_xT[ 5][dest] = xr1.y;
            s_xT[ 6][dest] = xr1.z; s_xT[ 7][dest] = xr1.w;
            s_xT[ 8][dest] = xr2.x; s_xT[ 9][dest] = xr2.y;
            s_xT[10][dest] = xr2.z; s_xT[11][dest] = xr2.w;
            s_xT[12][dest] = xr3.x; s_xT[13][dest] = xr3.y;
            s_xT[14][dest] = xr3.z; s_xT[15][dest] = xr3.w;
        }
        __syncthreads();

        // ---- branch-free inner loop: 9 compile-time-ib bucket loops ----
#pragma unroll
        for (int v = 0; v < 9; ++v) {
            for (int c = cum[v]; c < cum[v + 1]; c += 4) {
                const float4 xv = *(const float4*)&s_xT[zi][c];
                const float4 sA = *(const float4*)&s_shA[shi][c];
                const float4 sB = *(const float4*)&s_shB[shi][c];
                acc[v] = fmaf(xv.w, sA.w, fmaf(xv.z, sA.z,
                         fmaf(xv.y, sA.y, fmaf(xv.x, sA.x, acc[v]))));
                acc[v + 1] = fmaf(xv.w, sB.w, fmaf(xv.z, sB.z,
                             fmaf(xv.y, sB.y, fmaf(xv.x, sB.x, acc[v + 1]))));
            }
        }
    }

    // mean + stage to LDS for coalesced output
    const float scale = 1.0f / (float)max(cnt, 1);
#pragma unroll
    for (int b = 0; b < NB; ++b) s_out[fbase + b * w] = acc[b] * scale;
    __syncthreads();
    float4* og4 = (float4*)(out + (size_t)g * FEAT);
    const float4* so4 = (const float4*)s_out;
    for (int i = tid; i < FEAT / 4; i += 256) og4[i] = so4[i];
}

extern "C" void kernel_launch(void* const* d_in, const int* in_sizes, int n_in,
                              void* d_out, int out_size, void* d_ws, size_t ws_size,
                              hipStream_t stream) {
    const float* x   = (const float*)d_in[0];
    const float* pos = (const float*)d_in[1];
    const int* batch = (const int*)d_in[2];
    float* out = (float*)d_out;
    const int n_nodes = in_sizes[2];

    hipLaunchKernelGGL(yfe_kernel, dim3(NGRAPHS), dim3(256), 0, stream,
                       x, pos, batch, out, n_nodes);
}

// Round 4
// 65.590 us; speedup vs baseline: 4.8257x; 1.0022x over previous
//
#include <hip/hip_runtime.h>
#include <cmath>

#define NGRAPHS 1024
#define ZDIM 16
#define NB 10
#define SHD 16
#define FEAT 2560   // 16 z * 10 b * 16 sh
#define CHUNK 96           // max nodes staged per iteration (typ. segment ~49; loop handles overflow)
#define CSTRIDE 132        // >= CHUNK + 9*3 pad; 132 % 32 == 4 -> worst 2-way bank conflict (free)
#define WIN 1536           // windowed-search width: 6 elements per thread

// One block per graph. Thread ownership: tid -> (z = tid>>4, sh = tid&15).
// Radial basis is 2-sparse: only b in {ib, ib+1} nonzero per node, ib node-uniform.
// Nodes are BUCKETED BY ib at staging time; inner loop is 9 compile-time-ib
// mini-loops: 3x ds_read_b128 + 8 v_fmac per 4 nodes, no branches in the body.
//
// r4 trims (issue-bound regime, confirmed by r3's +4.5us from debranching):
//  - pad-only zeroing: zero the <=27 pad columns after counts are known,
//    instead of a 1584-float4 full-array zero pass (~0.5us device-wide).
//  - LDS-atomic bucket ranking (ds_add_rtn) replaces 9 wave ballots (~90
//    wave-instrs/block). Rank order within a bucket is arbitrary; any unique
//    rank is correct.
//  - pos loads issued BEFORE x loads (sh compute consumes pos first).
//  - #pragma unroll 2 on bucket loops.
__global__ __launch_bounds__(256) void yfe_kernel(
    const float* __restrict__ xin,
    const float* __restrict__ pos,
    const int* __restrict__ batch,
    float* __restrict__ out,
    int n_nodes)
{
    const int g = blockIdx.x;
    const int tid = threadIdx.x;
    const int n = n_nodes;

    __shared__ int s_red[12];
    __shared__ int s_bcnt[9];        // bucket counters (LDS atomics)
    __shared__ __align__(16) float s_xT[ZDIM][CSTRIDE];
    __shared__ __align__(16) float s_shA[SHD][CSTRIDE];   // sh[m] * bvA, bucket-permuted
    __shared__ __align__(16) float s_shB[SHD][CSTRIDE];   // sh[m] * bvB, bucket-permuted
    __shared__ __align__(16) float s_out[FEAT];

    if (tid < 9) s_bcnt[tid] = 0;    // visible after the first in-loop barrier

    int start, end;
    bool window_ok = (n >= WIN);
    if (window_ok) {
        // ---- windowed local search: one cold round, block-private lines ----
        const int ctr = (int)(((long long)(2 * g + 1) * n) >> 11);  // (g+0.5)*n/1024
        int p0 = ctr - WIN / 2;
        if (p0 < 0) p0 = 0;
        if (p0 > n - WIN) p0 = n - WIN;
        int vals[6];
#pragma unroll
        for (int k = 0; k < 6; ++k) vals[k] = batch[p0 + tid + k * 256];
        int wA = 0, wB = 0;
#pragma unroll
        for (int k = 0; k < 6; ++k) {
            wA += __popcll(__ballot(vals[k] < g));
            wB += __popcll(__ballot(vals[k] < g + 1));
        }
        if ((tid & 63) == 0) {
            s_red[tid >> 6]       = wA;   // identical across lanes of the wave
            s_red[4 + (tid >> 6)] = wB;
        }
        if (tid == 0)   s_red[8] = vals[0];   // batch[p0]
        if (tid == 255) s_red[9] = vals[5];   // batch[p0 + WIN - 1]
        __syncthreads();
        const int KA = s_red[0] + s_red[1] + s_red[2] + s_red[3];
        const int KB = s_red[4] + s_red[5] + s_red[6] + s_red[7];
        start = p0 + KA;
        end   = p0 + KB;
        // bracket validation: everything left of window < g, right of window >= g+1
        const bool left_ok  = (p0 == 0) || (s_red[8] < g);
        const bool right_ok = (p0 + WIN == n) || (s_red[9] >= g + 1);
        window_ok = left_ok && right_ok;      // block-uniform
        __syncthreads();                      // s_red reused below (fallback)
    }
    if (!window_ok) {
        // ---- exact fallback: original 2-level strided search ----
        {
            const int pos1 = (int)(((long long)tid * n) >> 8);
            const int v = batch[pos1];
            const unsigned long long balA = __ballot(v < g);
            const unsigned long long balB = __ballot(v < g + 1);
            if ((tid & 63) == 0) {
                s_red[tid >> 6]       = __popcll(balA);
                s_red[4 + (tid >> 6)] = __popcll(balB);
            }
        }
        __syncthreads();
        const int KA = s_red[0] + s_red[1] + s_red[2] + s_red[3];
        const int KB = s_red[4] + s_red[5] + s_red[6] + s_red[7];
        const int loA = (KA == 0) ? 0 : (int)(((long long)(KA - 1) * n) >> 8) + 1;
        const int hiA = (KA == 256) ? n : (int)(((long long)KA * n) >> 8);
        const int loB = (KB == 0) ? 0 : (int)(((long long)(KB - 1) * n) >> 8) + 1;
        const int hiB = (KB == 256) ? n : (int)(((long long)KB * n) >> 8);
        __syncthreads();
        const int pA = loA + tid;
        const int pB = loB + tid;
        const int prA = (pA < hiA) ? (batch[pA] < g) : 0;
        const int prB = (pB < hiB) ? (batch[pB] < g + 1) : 0;
        const unsigned long long balA = __ballot(prA);
        const unsigned long long balB = __ballot(prB);
        if ((tid & 63) == 0) {
            s_red[tid >> 6]       = __popcll(balA);
            s_red[4 + (tid >> 6)] = __popcll(balB);
        }
        __syncthreads();
        start = loA + s_red[0] + s_red[1] + s_red[2] + s_red[3];
        end   = loB + s_red[4] + s_red[5] + s_red[6] + s_red[7];
        __syncthreads();
    }
    const int cnt = end - start;

    const int zi  = tid >> 4;
    const int shi = tid & 15;
    const int l   = (shi >= 9) ? 3 : (shi >= 4) ? 2 : (shi >= 1) ? 1 : 0;
    const int m   = shi - l * l;
    const int w   = 2 * l + 1;
    const int off = (l == 0) ? 0 : (l == 1) ? 160 : (l == 2) ? 640 : 1440;
    const int fbase = off + zi * 10 * w + m;   // out index for b=0; +b*w

    float acc[NB];
#pragma unroll
    for (int b = 0; b < NB; ++b) acc[b] = 0.0f;

    // c = SMOOTH_FINITE_C * e^2 * sqrt(NBASIS)
    const float CB = (float)(1.14136 * 7.389056098930650 * 3.1622776601683795);

    for (int nb0 = start; nb0 < end; nb0 += CHUNK) {
        const int nrem = min(CHUNK, end - nb0);
        __syncthreads();   // protects prev-iter LDS reads AND s_bcnt zeroing

        // ---- node-thread compute: pos loads first (consumed first), then x ----
        int   my_ib = 9;         // 9 = "no bucket" for non-node lanes
        int   my_rank = 0;
        float4 xr0, xr1, xr2, xr3;
        float sh[SHD];
        float bvA = 0.0f, bvB = 0.0f;
        if (tid < nrem) {
            const int node = nb0 + tid;
            const float px = pos[node * 3 + 0];
            const float py = pos[node * 3 + 1];
            const float pz = pos[node * 3 + 2];
            const float4* xp = (const float4*)(xin + (size_t)node * ZDIM);
            xr0 = xp[0]; xr1 = xp[1]; xr2 = xp[2]; xr3 = xp[3];   // in flight under sh compute
            const float r2 = px * px + py * py + pz * pz;
            const float rinv = rsqrtf(r2);
            const float X = px * rinv, Y = py * rinv, Z = pz * rinv;
            const float x2 = X * X, y2 = Y * Y, z2 = Z * Z;
            const float x2z2 = x2 + z2;
            const float s3  = 1.7320508075688772f;
            const float s5  = 2.2360679774997896f;
            const float s7  = 2.6457513110645907f;
            const float s15 = 3.8729833462074170f;
            const float c42_6  = 1.0801234497346435f;   // sqrt(42)/6
            const float c168_8 = 1.6201851746019651f;   // sqrt(168)/8
            const float sh2_0 = s15 * X * Z;
            const float sh2_1 = s15 * X * Y;
            const float sh2_2 = s5 * (y2 - 0.5f * x2z2);
            const float sh2_3 = s15 * Y * Z;
            const float sh2_4 = 0.5f * s15 * (z2 - x2);
            sh[0]  = 1.0f;
            sh[1]  = s3 * X;
            sh[2]  = s3 * Y;
            sh[3]  = s3 * Z;
            sh[4]  = sh2_0;
            sh[5]  = sh2_1;
            sh[6]  = sh2_2;
            sh[7]  = sh2_3;
            sh[8]  = sh2_4;
            sh[9]  = c42_6 * (sh2_0 * Z + sh2_4 * X);
            sh[10] = s7 * sh2_0 * Y;
            sh[11] = c168_8 * (4.0f * y2 - x2z2) * X;
            sh[12] = 0.5f * s7 * Y * (2.0f * y2 - 3.0f * x2z2);
            sh[13] = c168_8 * Z * (4.0f * y2 - x2z2);
            sh[14] = s7 * sh2_4 * Y;
            sh[15] = c42_6 * (sh2_4 * Z - sh2_0 * X);
            // radial basis: t = 1.1*d; active b in (t-2, t) -> at most {ib, ib+1}
            const float d = r2 * rinv;     // sqrt(r2)
            const float t = d * 1.1f;
            int ib = (int)floorf(t) - 1;
            ib = min(max(ib, 0), 8);
            {
                const float u1 = t - (float)ib, u2 = (float)(ib + 2) - t;
                if (u1 > 0.0f && u2 > 0.0f) bvA = CB * __expf(-1.0f / u1 - 1.0f / u2);
                const float v1 = t - (float)(ib + 1), v2 = (float)(ib + 3) - t;
                if (v1 > 0.0f && v2 > 0.0f) bvB = CB * __expf(-1.0f / v1 - 1.0f / v2);
            }
            my_ib = ib;
            my_rank = atomicAdd(&s_bcnt[ib], 1);   // ds_add_rtn: unique rank, arbitrary order (OK)
        }
        __syncthreads();   // bucket counts final

        // every thread: raw counts + padded bucket starts (compile-time indexed)
        int cw[9], cum[10];
        cum[0] = 0;
#pragma unroll
        for (int v = 0; v < 9; ++v) {
            cw[v] = s_bcnt[v];
            cum[v + 1] = cum[v] + ((cw[v] + 3) & ~3);
        }

        // ---- pad-only zeroing: <=3 pad columns per bucket, 48 floats each.
        // Lanes 0-15 of waves 0/1/2 zero one row-set each (2-way bank conflict max).
#pragma unroll
        for (int v = 0; v < 9; ++v) {
            const int base = cum[v] + cw[v];
            const int pads = cum[v + 1] - base;   // 0..3 (0 for empty buckets)
#pragma unroll
            for (int p = 0; p < 3; ++p) {
                if (p < pads) {
                    const int col = base + p;
                    if (tid < 16)                      s_xT [tid      ][col] = 0.0f;
                    else if (tid >= 64 && tid < 80)    s_shA[tid - 64 ][col] = 0.0f;
                    else if (tid >= 128 && tid < 144)  s_shB[tid - 128][col] = 0.0f;
                }
            }
        }

        // ---- stage into bucket-permuted columns ----
        if (tid < nrem) {
            int dest = my_rank;
#pragma unroll
            for (int v = 0; v < 9; ++v)
                dest += (v < my_ib) ? ((cw[v] + 3) & ~3) : 0;
#pragma unroll
            for (int k = 0; k < SHD; ++k) {
                s_shA[k][dest] = sh[k] * bvA;
                s_shB[k][dest] = sh[k] * bvB;
            }
            s_xT[ 0][dest] = xr0.x; s_xT[ 1][dest] = xr0.y;
            s_xT[ 2][dest] = xr0.z; s_xT[ 3][dest] = xr0.w;
            s_xT[ 4][dest] = xr1.x; s_xT[ 5][dest] = xr1.y;
            s_xT[ 6][dest] = xr1.z; s_xT[ 7][dest] = xr1.w;
            s_xT[ 8][dest] = xr2.x; s_xT[ 9][dest] = xr2.y;
            s_xT[10][dest] = xr2.z; s_xT[11][dest] = xr2.w;
            s_xT[12][dest] = xr3.x; s_xT[13][dest] = xr3.y;
            s_xT[14][dest] = xr3.z; s_xT[15][dest] = xr3.w;
        }
        __syncthreads();

        // counters re-zero for the next chunk: happens during the inner-loop
        // phase (s_bcnt not read here); next top-of-loop barrier publishes it.
        if (tid < 9) s_bcnt[tid] = 0;

        // ---- branch-free inner loop: 9 compile-time-ib bucket loops ----
#pragma unroll
        for (int v = 0; v < 9; ++v) {
#pragma unroll 2
            for (int c = cum[v]; c < cum[v + 1]; c += 4) {
                const float4 xv = *(const float4*)&s_xT[zi][c];
                const float4 sA = *(const float4*)&s_shA[shi][c];
                const float4 sB = *(const float4*)&s_shB[shi][c];
                acc[v] = fmaf(xv.w, sA.w, fmaf(xv.z, sA.z,
                         fmaf(xv.y, sA.y, fmaf(xv.x, sA.x, acc[v]))));
                acc[v + 1] = fmaf(xv.w, sB.w, fmaf(xv.z, sB.z,
                             fmaf(xv.y, sB.y, fmaf(xv.x, sB.x, acc[v + 1]))));
            }
        }
    }

    // mean + stage to LDS for coalesced output
    const float scale = 1.0f / (float)max(cnt, 1);
#pragma unroll
    for (int b = 0; b < NB; ++b) s_out[fbase + b * w] = acc[b] * scale;
    __syncthreads();
    float4* og4 = (float4*)(out + (size_t)g * FEAT);
    const float4* so4 = (const float4*)s_out;
    for (int i = tid; i < FEAT / 4; i += 256) og4[i] = so4[i];
}

extern "C" void kernel_launch(void* const* d_in, const int* in_sizes, int n_in,
                              void* d_out, int out_size, void* d_ws, size_t ws_size,
                              hipStream_t stream) {
    const float* x   = (const float*)d_in[0];
    const float* pos = (const float*)d_in[1];
    const int* batch = (const int*)d_in[2];
    float* out = (float*)d_out;
    const int n_nodes = in_sizes[2];

    hipLaunchKernelGGL(yfe_kernel, dim3(NGRAPHS), dim3(256), 0, stream,
                       x, pos, batch, out, n_nodes);
}